// Round 1
// 663.504 us; speedup vs baseline: 1.3946x; 1.3946x over previous
//
#include <hip/hip_runtime.h>
#include <cstddef>
#include <cstdint>

#define BATCH_N 32768
#define OUT_DIM 10

typedef unsigned short u16;
typedef __attribute__((ext_vector_type(8))) short short8;
typedef __attribute__((ext_vector_type(4))) float f32x4;

__device__ __forceinline__ float bf2f(u16 h) {
    return __uint_as_float(((uint32_t)h) << 16);
}
__device__ __forceinline__ u16 f2bf(float v) {
    uint32_t b = __float_as_uint(v);
    b += 0x7FFFu + ((b >> 16) & 1u);
    return (u16)(b >> 16);
}
__device__ __forceinline__ void fsplit(float v, u16& h, u16& l) {
    h = f2bf(v);
    l = f2bf(v - bf2f(h));
}
__device__ __forceinline__ float tanh_fast(float x) {
    float e = __expf(2.f * x);        // inf -> 1, 0 -> -1 : robust
    return 1.f - 2.f / (e + 1.f);
}

// ============================================================================
// MEGA-FUSED NETWORK KERNEL (R7: 128 rows/block, 1024 threads = 16 waves,
// 1 block/CU, 4 waves/SIMD).  Rationale: halve per-CU weight traffic
// (2.15 GB total vs 4.3 GB) and shrink per-ks B-fragment set to 4 loads
// (16 VGPR) so a depth-1 ping-pong prefetch fits the 128-reg budget
// (acc[8][2]=64 + B[2][4]=32 + misc).
// State [128 x 512] bf16 in LDS; A-fragment layout: (m,k) ->
// state[(k>>5)*4096 + (m>>4)*512 + (((k>>3)&3)*16 + (m&15))*8 + (k&7)].
// Weights Wc[layer][col c][1024]: k 0..511 hi bf16, 512..1023 lo bf16.
// Wave owns 32 cols (2 x 16): c = wave*32 + nt*16 + fl.  Columns
// interleaved: c=2u -> z0[u], c=2u+1 -> z1[u]; epilogue adds cc[c], hands
// tanh(z0) even->odd lane via shfl_xor(1), writes v0'=z0, w'=z1+tanh(z0).
// ============================================================================
__global__ __launch_bounds__(1024, 4)
void meganet(const float* __restrict__ X,
             const u16* __restrict__ Wi,        // [256 u][1600] hi|lo
             const float* __restrict__ b_in,
             const u16* __restrict__ Wc,        // [8][512 c][1024] hi|lo
             const float* __restrict__ cc,
             const float* __restrict__ Wo, const float* __restrict__ bo,
             float* __restrict__ out)
{
    __shared__ u16 state[65536];     // 128 KB
    __shared__ float aux[2560];      // 10 KB: x staging, later W_out copy
    const int t = threadIdx.x;
    const int wave = t >> 6, lane = t & 63;
    const int fl = lane & 15, kq = lane >> 4;
    const int b0 = blockIdx.x * 128;

    // ---------------- input stage: v0 = x @ W_in + b_in (K=784, pad 800) ----
    // 16 waves x 16 cols; acc 8x1; x + Wi fragments prefetched 1 step ahead.
    f32x4 ai[8];
#pragma unroll
    for (int a = 0; a < 8; ++a) ai[a] = (f32x4){0.f, 0.f, 0.f, 0.f};

    const u16* bpIn = Wi + (size_t)(wave * 16 + fl) * 1600 + kq * 8;

    u16* xbuf = (u16*)aux;           // 4096 u16 chunk buffer (8 KB)
    const int xr = t >> 3;           // row 0..127
    const int xk = (t & 7) * 4;      // 0..28 step 4
    const size_t xrow = (size_t)(b0 + xr) * 784;
    const int xoff = (xr >> 4) * 512 + ((xk >> 3) * 16 + (xr & 15)) * 8 + (xk & 7);

    float4 xa = *(const float4*)(X + xrow + xk);       // k0=0 chunk (xk<=28)
    short8 IB[2][2];
    IB[0][0] = *(const short8*)(bpIn);
    IB[0][1] = *(const short8*)(bpIn + 800);

#pragma unroll
    for (int ki = 0; ki < 25; ++ki) {
        const int k0 = ki * 32;
        const int cur = ki & 1, nxt = cur ^ 1;
        __syncthreads();                 // xbuf free (prev MFMA phase done)
        ushort4 ha;
        ha.x = f2bf(xa.x); ha.y = f2bf(xa.y); ha.z = f2bf(xa.z); ha.w = f2bf(xa.w);
        *(ushort4*)&xbuf[xoff] = ha;
        if (ki < 24) {                   // prefetch next chunk (hides HBM/L2)
            const int gk = k0 + 32 + xk;
            const int ga = (gk <= 780) ? gk : 780;   // clamp; Wi packs 0 for k>=784
            xa = *(const float4*)(X + xrow + ga);
            IB[nxt][0] = *(const short8*)(bpIn + k0 + 32);
            IB[nxt][1] = *(const short8*)(bpIn + 800 + k0 + 32);
        }
        __syncthreads();                 // xbuf ready
#pragma unroll
        for (int mt = 0; mt < 8; ++mt) {
            short8 af = *(const short8*)&xbuf[mt * 512 + lane * 8];
            ai[mt] = __builtin_amdgcn_mfma_f32_16x16x32_bf16(af, IB[cur][0], ai[mt], 0, 0, 0);
            ai[mt] = __builtin_amdgcn_mfma_f32_16x16x32_bf16(af, IB[cur][1], ai[mt], 0, 0, 0);
        }
    }

    // layer-0 ks=0 weight prefetch: global, independent of LDS -> issue early
    const u16* bp0 = Wc + (size_t)(wave * 32 + fl) * 1024 + kq * 8;
    const u16* bp1 = bp0 + 16 * 1024;
    short8 B[2][4];
    B[0][0] = *(const short8*)(bp0);
    B[0][1] = *(const short8*)(bp0 + 512);
    B[0][2] = *(const short8*)(bp1);
    B[0][3] = *(const short8*)(bp1 + 512);

    // input epilogue: state v0 (k=u), w = 2*tanh(v0) (k=256+u)
    {
        const float bi = b_in[wave * 16 + fl];
        const int u = wave * 16 + fl;
        const int slab = u >> 5;
        const int cbase = ((u >> 3) & 3) * 128 + (u & 7);
#pragma unroll
        for (int mt = 0; mt < 8; ++mt) {
#pragma unroll
            for (int r = 0; r < 4; ++r) {
                float v = ai[mt][r] + bi;
                float w = 2.f * tanh_fast(v);
                const int base = mt * 512 + (kq * 4 + r) * 8 + cbase;
                state[slab * 4096 + base] = f2bf(v);
                state[(8 + slab) * 4096 + base] = f2bf(w);
            }
        }
    }

    // ---------------- 8 implicit layers ----------------
    for (int L = 0; L < 8; ++L) {
        const float ccv0 = cc[L * 512 + wave * 32 + fl];
        const float ccv1 = cc[L * 512 + wave * 32 + 16 + fl];
        f32x4 acc[8][2];
#pragma unroll
        for (int a = 0; a < 8; ++a) {
            acc[a][0] = (f32x4){0.f, 0.f, 0.f, 0.f};
            acc[a][1] = (f32x4){0.f, 0.f, 0.f, 0.f};
        }
        __syncthreads();   // state ready
#pragma unroll
        for (int ks = 0; ks < 16; ++ks) {
            const int cur = ks & 1, nxt = cur ^ 1;
            if (ks < 15) {             // prefetch next K-step (4 x 16B, compile-time idx)
                B[nxt][0] = *(const short8*)(bp0 + (ks + 1) * 32);
                B[nxt][1] = *(const short8*)(bp0 + 512 + (ks + 1) * 32);
                B[nxt][2] = *(const short8*)(bp1 + (ks + 1) * 32);
                B[nxt][3] = *(const short8*)(bp1 + 512 + (ks + 1) * 32);
            } else {                   // prefetch next layer's ks=0 across epilogue
                bp0 += 524288; bp1 += 524288;
                if (L < 7) {
                    B[nxt][0] = *(const short8*)(bp0);
                    B[nxt][1] = *(const short8*)(bp0 + 512);
                    B[nxt][2] = *(const short8*)(bp1);
                    B[nxt][3] = *(const short8*)(bp1 + 512);
                }
            }
#pragma unroll
            for (int mt = 0; mt < 8; ++mt) {
                short8 af = *(const short8*)&state[ks * 4096 + mt * 512 + lane * 8];
                acc[mt][0] = __builtin_amdgcn_mfma_f32_16x16x32_bf16(af, B[cur][0], acc[mt][0], 0, 0, 0);
                acc[mt][0] = __builtin_amdgcn_mfma_f32_16x16x32_bf16(af, B[cur][1], acc[mt][0], 0, 0, 0);
                acc[mt][1] = __builtin_amdgcn_mfma_f32_16x16x32_bf16(af, B[cur][2], acc[mt][1], 0, 0, 0);
                acc[mt][1] = __builtin_amdgcn_mfma_f32_16x16x32_bf16(af, B[cur][3], acc[mt][1], 0, 0, 0);
            }
        }
        __syncthreads();   // all state reads done; safe to overwrite
        const int p = fl & 1;
        const int uq = fl >> 1;
#pragma unroll
        for (int nt = 0; nt < 2; ++nt) {
            const int u = wave * 16 + nt * 8 + uq;
            const int slab = p ? (8 + (u >> 5)) : (u >> 5);
            const int cbase = slab * 4096 + ((u >> 3) & 3) * 128 + (u & 7);
            const float cv = nt ? ccv1 : ccv0;
#pragma unroll
            for (int mt = 0; mt < 8; ++mt) {
#pragma unroll
                for (int r = 0; r < 4; ++r) {
                    float val = acc[mt][nt][r] + cv;
                    float tv = tanh_fast(val);
                    float tp = __shfl_xor(tv, 1);
                    float outv = p ? (val + tp) : val;
                    state[cbase + mt * 512 + (kq * 4 + r) * 8] = f2bf(outv);
                }
            }
        }
    }

    // ---------------- output stage: out = v0 @ W_out + b_out ----------------
    __syncthreads();
    for (int i = t; i < 2560; i += 1024) aux[i] = Wo[i];
    __syncthreads();
    {
        const int m = t >> 3;        // 0..127
        const int o = t & 7;
        float s = bo[o];
        for (int kb = 0; kb < 256; kb += 8) {
            const int off = (kb >> 5) * 4096 + (m >> 4) * 512 +
                            (((kb >> 3) & 3) * 16 + (m & 15)) * 8;
            ushort4 h0 = *(const ushort4*)&state[off];
            ushort4 h1 = *(const ushort4*)&state[off + 4];
            s += bf2f(h0.x) * aux[(kb + 0) * 10 + o] + bf2f(h0.y) * aux[(kb + 1) * 10 + o]
               + bf2f(h0.z) * aux[(kb + 2) * 10 + o] + bf2f(h0.w) * aux[(kb + 3) * 10 + o]
               + bf2f(h1.x) * aux[(kb + 4) * 10 + o] + bf2f(h1.y) * aux[(kb + 5) * 10 + o]
               + bf2f(h1.z) * aux[(kb + 6) * 10 + o] + bf2f(h1.w) * aux[(kb + 7) * 10 + o];
        }
        out[(size_t)(b0 + m) * 10 + o] = s;
    }
    if (t < 256) {
        const int m = t >> 1;
        const int o = 8 + (t & 1);
        float s = bo[o];
        for (int kb = 0; kb < 256; kb += 8) {
            const int off = (kb >> 5) * 4096 + (m >> 4) * 512 +
                            (((kb >> 3) & 3) * 16 + (m & 15)) * 8;
            ushort4 h0 = *(const ushort4*)&state[off];
            ushort4 h1 = *(const ushort4*)&state[off + 4];
            s += bf2f(h0.x) * aux[(kb + 0) * 10 + o] + bf2f(h0.y) * aux[(kb + 1) * 10 + o]
               + bf2f(h0.z) * aux[(kb + 2) * 10 + o] + bf2f(h0.w) * aux[(kb + 3) * 10 + o]
               + bf2f(h1.x) * aux[(kb + 4) * 10 + o] + bf2f(h1.y) * aux[(kb + 5) * 10 + o]
               + bf2f(h1.z) * aux[(kb + 6) * 10 + o] + bf2f(h1.w) * aux[(kb + 7) * 10 + o];
        }
        out[(size_t)(b0 + m) * 10 + o] = s;
    }
}

// ============================================================================
// fp32 prep: D[u,v] = EPI(sum_k A[k][u]*B[k][v]) batched over 8
// R7: 32x32 tiles -> 512 blocks (2/CU, 2 waves/SIMD) instead of 128;
// register-prefetched staging hides L2 latency; per-thread work 4x smaller.
// ============================================================================
template<int EPI>
__launch_bounds__(256)
__global__ void gemm256c(float* __restrict__ D, const float* __restrict__ A,
                         const float* __restrict__ Bm, const float* __restrict__ E)
{
    __shared__ float As[32][36];     // +4 pad: conflict-free f4 stores / f2 reads
    __shared__ float Bs[32][36];
    const int i = blockIdx.z;
    const size_t off = (size_t)i * 65536;
    const float* Ai = A + off;
    const float* Bi = Bm + off;
    const int t  = threadIdx.x;
    const int tx = t & 15, ty = t >> 4;
    const int u0 = blockIdx.y * 32, v0 = blockIdx.x * 32;
    const int lk = t >> 3, lv = (t & 7) << 2;

    float acc[2][2] = {{0.f, 0.f}, {0.f, 0.f}};
    float4 an = *(const float4*)(Ai + (size_t)lk * 256 + u0 + lv);
    float4 bn = *(const float4*)(Bi + (size_t)lk * 256 + v0 + lv);

    for (int k0 = 0; k0 < 256; k0 += 32) {
        if (k0) __syncthreads();
        *(float4*)&As[lk][lv] = an;
        *(float4*)&Bs[lk][lv] = bn;
        if (k0 < 224) {
            an = *(const float4*)(Ai + (size_t)(k0 + 32 + lk) * 256 + u0 + lv);
            bn = *(const float4*)(Bi + (size_t)(k0 + 32 + lk) * 256 + v0 + lv);
        }
        __syncthreads();
#pragma unroll
        for (int kk = 0; kk < 32; ++kk) {
            float2 a2 = *(const float2*)&As[kk][ty * 2];
            float2 b2 = *(const float2*)&Bs[kk][tx * 2];
            acc[0][0] += a2.x * b2.x; acc[0][1] += a2.x * b2.y;
            acc[1][0] += a2.y * b2.x; acc[1][1] += a2.y * b2.y;
        }
    }

#pragma unroll
    for (int m = 0; m < 2; ++m) {
        const int u = u0 + ty * 2 + m;
        const size_t idx = off + (size_t)u * 256 + v0 + tx * 2;
        float2 r;
        if (EPI == 0) {
            r.x = acc[m][0]; r.y = acc[m][1];
        } else if (EPI == 1) {
            r.x = acc[m][0] + ((u == v0 + tx * 2)     ? 2.f : 0.f);
            r.y = acc[m][1] + ((u == v0 + tx * 2 + 1) ? 2.f : 0.f);
        } else {
            float2 e = *(const float2*)&E[idx];
            r.x = 2.f * e.x - acc[m][0];
            r.y = 2.f * e.y - acc[m][1];
        }
        *(float2*)&D[idx] = r;
    }
}

// transpose Bt[k][u] = B0[u][k] : 64 blocks (8 matrices x 8 row-slabs)
__launch_bounds__(256)
__global__ void prep_bt(const float* __restrict__ B0, float* __restrict__ Bt)
{
    __shared__ float tl[32][33];
    const int i = blockIdx.x;
    const int s = blockIdx.y;
    const float* S = B0 + (size_t)i * 65536;
    float* D = Bt + (size_t)i * 65536;
    const int t = threadIdx.x;
    const int tx = t & 31, ty = t >> 5;   // 32 x 8
    const int u0 = s * 32;
    for (int k0 = 0; k0 < 256; k0 += 32) {
        __syncthreads();
#pragma unroll
        for (int r = 0; r < 32; r += 8)
            tl[ty + r][tx] = S[(size_t)(u0 + ty + r) * 256 + k0 + tx];
        __syncthreads();
#pragma unroll
        for (int r = 0; r < 32; r += 8)
            D[(size_t)(k0 + ty + r) * 256 + u0 + tx] = tl[tx][ty + r];
    }
}

// alpha = ||C||_inf, then quadratic NS seed X0 = a I + b C (rho0 ~ 0.1)
__launch_bounds__(256)
__global__ void prep_alpha_seed(const float* __restrict__ C, float* __restrict__ X)
{
    __shared__ float red[256];
    const int i = blockIdx.x;
    const int t = threadIdx.x;
    float s = 0.f;
    for (int v = 0; v < 256; ++v) s += fabsf(C[(size_t)i * 65536 + (size_t)v * 256 + t]);
    red[t] = s;
    __syncthreads();
    for (int off = 128; off > 0; off >>= 1) {
        if (t < off) red[t] = fmaxf(red[t], red[t + off]);
        __syncthreads();
    }
    const float bt = red[0];                       // >= lambda_max; lambda_min >= 2
    const float r = (2.f + bt) * (2.f + bt) / (8.f * bt);
    const float e = (r - 1.f) / (r + 1.f);
    const float b = -(1.f - e) / (2.f * bt);
    const float a = -b * (2.f + bt);
    for (int idx = t; idx < 65536; idx += 256) {
        const int r_ = idx >> 8, c_ = idx & 255;
        X[(size_t)i * 65536 + idx] = b * C[(size_t)i * 65536 + idx] + ((r_ == c_) ? a : 0.f);
    }
}

// bq = 0.1*B0^T q, c1 = M bq (odd cc slots), c0 = 0.1 q - B c1 (even) : 1 launch
__launch_bounds__(256)
__global__ void prep_cc2(const float* __restrict__ M, const float* __restrict__ Bt,
                         const float* __restrict__ B0, const float* __restrict__ q,
                         float* __restrict__ cc)
{
    __shared__ float qs[256];
    __shared__ float vs[256];
    __shared__ float c1s[256];
    const int i = blockIdx.x;
    const int u = threadIdx.x;
    qs[u] = q[i * 256 + u];
    __syncthreads();
    float s0 = 0.f;
    for (int k = 0; k < 256; ++k) s0 += B0[(size_t)i * 65536 + (size_t)k * 256 + u] * qs[k];
    vs[u] = 0.1f * s0;
    __syncthreads();
    float s = 0.f;
    for (int k = 0; k < 256; ++k) s += M[(size_t)i * 65536 + (size_t)k * 256 + u] * vs[k];
    c1s[u] = s;
    cc[i * 512 + 2 * u + 1] = s;
    __syncthreads();
    float s2 = 0.f;
    for (int k = 0; k < 256; ++k) s2 += Bt[(size_t)i * 65536 + (size_t)k * 256 + u] * c1s[k];
    cc[i * 512 + 2 * u] = 0.1f * qs[u] - s2;
}

// Wc[i][c][1024] hi|lo pack (interleaved z0/z1 columns)
__launch_bounds__(256)
__global__ void pack_wcomb(const float* __restrict__ P, const float* __restrict__ R,
                           const float* __restrict__ M, u16* __restrict__ W)
{
    const int i = blockIdx.y;
    const int e = blockIdx.x * 256 + threadIdx.x;   // 0..262143
    const int c = e >> 9, k = e & 511;
    const int u = c >> 1, parity = c & 1;
    const size_t off = (size_t)i * 65536;
    float v;
    if (parity == 0) {
        if (k < 256) v = ((u == k) ? 1.f : 0.f) - R[off + (size_t)u * 256 + k];
        else         v = -P[off + (size_t)(k - 256) * 256 + u];
    } else {
        if (k < 256) v = P[off + (size_t)u * 256 + k];
        else         v = M[off + (size_t)u * 256 + (k - 256)];
    }
    u16 h, l; fsplit(v, h, l);
    const size_t o = (size_t)i * 524288 + (size_t)c * 1024 + k;
    W[o] = h; W[o + 512] = l;
}

// W_in [784][256] -> Wi[256 u][1600] hi|lo (transposed, zero-padded)
__global__ void pack_win(const float* __restrict__ Wsrc, u16* __restrict__ W)
{
    int k = blockIdx.x * 256 + threadIdx.x;
    int u = blockIdx.y;
    if (k >= 800) return;
    float v = (k < 784) ? Wsrc[(size_t)k * 256 + u] : 0.f;
    u16 h, l; fsplit(v, h, l);
    W[(size_t)u * 1600 + k] = h;
    W[(size_t)u * 1600 + 800 + k] = l;
}

extern "C" void kernel_launch(void* const* d_in, const int* in_sizes, int n_in,
                              void* d_out, int out_size, void* d_ws, size_t ws_size,
                              hipStream_t stream)
{
    const float* x     = (const float*)d_in[0];
    const float* W_in  = (const float*)d_in[1];
    const float* b_in  = (const float*)d_in[2];
    const float* B0    = (const float*)d_in[3];
    const float* q     = (const float*)d_in[4];
    const float* W_out = (const float*)d_in[5];
    const float* b_out = (const float*)d_in[6];

    u16* Wc = (u16*)d_ws;                  // 8 * 524288 u16 = 8 MB
    u16* Wi = Wc + 8 * 524288;             // 256*1600
    float* bq = (float*)(Wi + 409600);     // (slot kept for layout stability)
    float* cc = bq + 2048;                 // 8*512
    float* F  = cc + 4096;                 // prep scratch: 7 * 524288 floats
    float* Bt = F;
    float* C  = F + 1 * 524288;
    float* X  = F + 2 * 524288;
    float* X2 = F + 3 * 524288;
    float* Y  = F + 4 * 524288;
    float* P  = F + 5 * 524288;
    float* R  = F + 6 * 524288;

    // ---- per-layer matrix prep (fp32) ----
    prep_bt<<<dim3(8, 8), 256, 0, stream>>>(B0, Bt);
    gemm256c<1><<<dim3(8, 8, 8), 256, 0, stream>>>(C, B0, B0, nullptr); // C = B^T B + 2I
    prep_alpha_seed<<<8, 256, 0, stream>>>(C, X);
    float* Xc = X; float* Xn = X2;
    for (int it = 0; it < 3; ++it) {   // Newton-Schulz: X <- 2X - X C X
        gemm256c<0><<<dim3(8, 8, 8), 256, 0, stream>>>(Y, C, Xc, nullptr);
        gemm256c<2><<<dim3(8, 8, 8), 256, 0, stream>>>(Xn, Xc, Y, Xc);
        float* tmp = Xc; Xc = Xn; Xn = tmp;
    }
    // Xc = M = (B^T B + 2I)^{-1} (symmetric)
    gemm256c<0><<<dim3(8, 8, 8), 256, 0, stream>>>(P, Xc, Bt, nullptr);  // P = M B^T
    gemm256c<0><<<dim3(8, 8, 8), 256, 0, stream>>>(R, Bt, P, nullptr);   // R = B P
    prep_cc2<<<8, 256, 0, stream>>>(Xc, Bt, B0, q, cc);

    // ---- weight packs ----
    pack_wcomb<<<dim3(1024, 8), 256, 0, stream>>>(P, R, Xc, Wc);
    pack_win<<<dim3(4, 256), 256, 0, stream>>>(W_in, Wi);

    // ---- the whole network in one kernel ----
    meganet<<<BATCH_N / 128, 1024, 0, stream>>>(
        x, Wi, b_in, Wc, cc, W_out, b_out, (float*)d_out);
}

// Round 2
// 492.097 us; speedup vs baseline: 1.8803x; 1.3483x over previous
//
#include <hip/hip_runtime.h>
#include <cstddef>
#include <cstdint>

#define BATCH_N 32768
#define OUT_DIM 10

typedef unsigned short u16;
typedef __attribute__((ext_vector_type(8))) _Float16 half8;
typedef __attribute__((ext_vector_type(4))) float f32x4;

__device__ __forceinline__ u16 f2h(float v) {
    _Float16 h = (_Float16)v;                 // RTN
    return __builtin_bit_cast(u16, h);
}
__device__ __forceinline__ float h2f(u16 h) {
    return (float)__builtin_bit_cast(_Float16, h);
}
__device__ __forceinline__ float tanh_fast(float x) {
    float e = __expf(2.f * x);        // inf -> 1, 0 -> -1 : robust
    return 1.f - 2.f / (e + 1.f);
}

// ============================================================================
// MEGA-FUSED NETWORK KERNEL (R8: full f16 single-pass).
// Precision model: state f16 (eps 2^-11, 8x finer than prior bf16) and
// weights f16 single (no hi/lo split) -> HALF the MFMAs of R7 with LOWER
// total error (prior absmax was state-bf16-quantization dominated).
// 128 rows/block, 1024 threads = 16 waves, 1 block/CU, 4 waves/SIMD.
// State [128 x 512] f16 in LDS; A-fragment layout: (m,k) ->
// state[(k>>5)*4096 + (m>>4)*512 + (((k>>3)&3)*16 + (m&15))*8 + (k&7)].
// Weights Wc[layer][c][512] f16, c<256 -> z0 row u=c, c>=256 -> z1 row u=c-256
// (de-interleaved: thread owns z0[u] AND z1[u] -> tanh once, no shfl).
// Wave owns u = wave*16 + fl; acc[8][2] = 64 AGPR; B[2][2] ping-pong prefetch.
// Input stage: x double-buffered in aux (one barrier/chunk), Wi f16 [256][800].
// ============================================================================
__global__ __launch_bounds__(1024, 4)
void meganet(const float* __restrict__ X,
             const u16* __restrict__ Wi,        // [256 u][800 k] f16
             const float* __restrict__ b_in,
             const u16* __restrict__ Wc,        // [8][512 c][512 k] f16
             const float* __restrict__ cc,      // [8][512]: [0..255]=c0, [256..511]=c1
             const float* __restrict__ Wo, const float* __restrict__ bo,
             float* __restrict__ out)
{
    __shared__ u16 state[65536];     // 128 KB
    __shared__ float aux[4096];      // 16 KB: x double-buffer, later W_out copy
    const int t = threadIdx.x;
    const int wave = t >> 6, lane = t & 63;
    const int fl = lane & 15, kq = lane >> 4;
    const int b0 = blockIdx.x * 128;

    // ---------------- input stage: v0 = x @ W_in + b_in (K=784, pad 800) ----
    // 16 waves x 16 cols; acc 8x1; x staged f16, double-buffered (1 barrier/ki)
    f32x4 ai[8];
#pragma unroll
    for (int a = 0; a < 8; ++a) ai[a] = (f32x4){0.f, 0.f, 0.f, 0.f};

    const u16* bpIn = Wi + (size_t)(wave * 16 + fl) * 800 + kq * 8;

    u16* xbuf = (u16*)aux;           // 2 x 4096 u16 chunk buffers
    const int xr = t >> 3;           // row 0..127
    const int xk = (t & 7) * 4;      // 0..28 step 4
    const size_t xrow = (size_t)(b0 + xr) * 784;
    const int xoff = (xr >> 4) * 512 + ((xk >> 3) * 16 + (xr & 15)) * 8 + (xk & 7);

    half8 IB[2];
    float4 xa;
    {   // prologue: chunk0 -> buf0 (own slot; published by first barrier)
        float4 x0 = *(const float4*)(X + xrow + xk);
        ushort4 h;
        h.x = f2h(x0.x); h.y = f2h(x0.y); h.z = f2h(x0.z); h.w = f2h(x0.w);
        *(ushort4*)&xbuf[xoff] = h;
        xa = *(const float4*)(X + xrow + 32 + xk);     // chunk 1
        IB[0] = *(const half8*)(bpIn);                 // chunk 0 weights
    }

#pragma unroll
    for (int ki = 0; ki < 25; ++ki) {
        const int cur = ki & 1, nxt = cur ^ 1;
        __syncthreads();                 // buf[cur] ready; buf[nxt] reads done
        if (ki < 24) {                   // stage chunk ki+1 into buf[nxt]
            ushort4 h;
            h.x = f2h(xa.x); h.y = f2h(xa.y); h.z = f2h(xa.z); h.w = f2h(xa.w);
            *(ushort4*)&xbuf[nxt * 4096 + xoff] = h;
            if (ki < 23) {               // load chunk ki+2 (depth-2)
                const int gk = (ki + 2) * 32 + xk;
                const int ga = (gk <= 780) ? gk : 780;   // Wi packs 0 for k>=784
                xa = *(const float4*)(X + xrow + ga);
            }
            IB[nxt] = *(const half8*)(bpIn + (ki + 1) * 32);
        }
        const u16* rb = xbuf + cur * 4096;
#pragma unroll
        for (int mt = 0; mt < 8; ++mt) {
            half8 af = *(const half8*)&rb[mt * 512 + lane * 8];
            ai[mt] = __builtin_amdgcn_mfma_f32_16x16x32_f16(af, IB[cur], ai[mt], 0, 0, 0);
        }
    }

    // layer-0 ks=0 weight prefetch: global, independent of LDS -> issue early
    const u16* bp0 = Wc + (size_t)(wave * 16 + fl) * 512 + kq * 8;   // z0 row u
    const u16* bp1 = bp0 + 131072;                                   // z1 row u
    half8 B[2][2];
    B[0][0] = *(const half8*)(bp0);
    B[0][1] = *(const half8*)(bp1);

    // input epilogue: state v0 (k=u), w = 2*tanh(v0) (k=256+u)
    {
        const float bi = b_in[wave * 16 + fl];
        const int u = wave * 16 + fl;
        const int slab = u >> 5;
        const int cbase = ((u >> 3) & 3) * 128 + (u & 7);
#pragma unroll
        for (int mt = 0; mt < 8; ++mt) {
#pragma unroll
            for (int r = 0; r < 4; ++r) {
                float v = ai[mt][r] + bi;
                float w = 2.f * tanh_fast(v);
                const int base = mt * 512 + (kq * 4 + r) * 8 + cbase;
                state[slab * 4096 + base] = f2h(v);
                state[(8 + slab) * 4096 + base] = f2h(w);
            }
        }
    }

    // ---------------- 8 implicit layers ----------------
    for (int L = 0; L < 8; ++L) {
        const float ccv0 = cc[L * 512 + wave * 16 + fl];
        const float ccv1 = cc[L * 512 + 256 + wave * 16 + fl];
        f32x4 acc[8][2];
#pragma unroll
        for (int a = 0; a < 8; ++a) {
            acc[a][0] = (f32x4){0.f, 0.f, 0.f, 0.f};
            acc[a][1] = (f32x4){0.f, 0.f, 0.f, 0.f};
        }
        __syncthreads();   // state ready
#pragma unroll
        for (int ks = 0; ks < 16; ++ks) {
            const int cur = ks & 1, nxt = cur ^ 1;
            if (ks < 15) {             // prefetch next K-step (2 x 16B)
                B[nxt][0] = *(const half8*)(bp0 + (ks + 1) * 32);
                B[nxt][1] = *(const half8*)(bp1 + (ks + 1) * 32);
            } else {                   // prefetch next layer's ks=0 across epilogue
                bp0 += 262144; bp1 += 262144;
                if (L < 7) {
                    B[nxt][0] = *(const half8*)(bp0);
                    B[nxt][1] = *(const half8*)(bp1);
                }
            }
#pragma unroll
            for (int mt = 0; mt < 8; ++mt) {
                half8 af = *(const half8*)&state[ks * 4096 + mt * 512 + lane * 8];
                acc[mt][0] = __builtin_amdgcn_mfma_f32_16x16x32_f16(af, B[cur][0], acc[mt][0], 0, 0, 0);
                acc[mt][1] = __builtin_amdgcn_mfma_f32_16x16x32_f16(af, B[cur][1], acc[mt][1], 0, 0, 0);
            }
        }
        __syncthreads();   // all state reads done; safe to overwrite
        // epilogue: thread owns z0[u] and z1[u] -> tanh once, no shfl
        {
            const int u = wave * 16 + fl;
            const int slab = u >> 5;
            const int cbase = ((u >> 3) & 3) * 128 + (u & 7);
#pragma unroll
            for (int mt = 0; mt < 8; ++mt) {
#pragma unroll
                for (int r = 0; r < 4; ++r) {
                    float z0 = acc[mt][0][r] + ccv0;
                    float z1 = acc[mt][1][r] + ccv1;
                    float tv = tanh_fast(z0);
                    const int base = mt * 512 + (kq * 4 + r) * 8 + cbase;
                    state[slab * 4096 + base] = f2h(z0);
                    state[(8 + slab) * 4096 + base] = f2h(z1 + tv);
                }
            }
        }
    }

    // ---------------- output stage: out = v0 @ W_out + b_out ----------------
    __syncthreads();
    for (int i = t; i < 2560; i += 1024) aux[i] = Wo[i];
    __syncthreads();
    {
        const int m = t >> 3;        // 0..127
        const int o = t & 7;
        float s = bo[o];
        for (int kb = 0; kb < 256; kb += 8) {
            const int off = (kb >> 5) * 4096 + (m >> 4) * 512 +
                            (((kb >> 3) & 3) * 16 + (m & 15)) * 8;
            ushort4 h0 = *(const ushort4*)&state[off];
            ushort4 h1 = *(const ushort4*)&state[off + 4];
            s += h2f(h0.x) * aux[(kb + 0) * 10 + o] + h2f(h0.y) * aux[(kb + 1) * 10 + o]
               + h2f(h0.z) * aux[(kb + 2) * 10 + o] + h2f(h0.w) * aux[(kb + 3) * 10 + o]
               + h2f(h1.x) * aux[(kb + 4) * 10 + o] + h2f(h1.y) * aux[(kb + 5) * 10 + o]
               + h2f(h1.z) * aux[(kb + 6) * 10 + o] + h2f(h1.w) * aux[(kb + 7) * 10 + o];
        }
        out[(size_t)(b0 + m) * 10 + o] = s;
    }
    if (t < 256) {
        const int m = t >> 1;
        const int o = 8 + (t & 1);
        float s = bo[o];
        for (int kb = 0; kb < 256; kb += 8) {
            const int off = (kb >> 5) * 4096 + (m >> 4) * 512 +
                            (((kb >> 3) & 3) * 16 + (m & 15)) * 8;
            ushort4 h0 = *(const ushort4*)&state[off];
            ushort4 h1 = *(const ushort4*)&state[off + 4];
            s += h2f(h0.x) * aux[(kb + 0) * 10 + o] + h2f(h0.y) * aux[(kb + 1) * 10 + o]
               + h2f(h0.z) * aux[(kb + 2) * 10 + o] + h2f(h0.w) * aux[(kb + 3) * 10 + o]
               + h2f(h1.x) * aux[(kb + 4) * 10 + o] + h2f(h1.y) * aux[(kb + 5) * 10 + o]
               + h2f(h1.z) * aux[(kb + 6) * 10 + o] + h2f(h1.w) * aux[(kb + 7) * 10 + o];
        }
        out[(size_t)(b0 + m) * 10 + o] = s;
    }
}

// ============================================================================
// fp32 prep: D[u,v] = EPI(sum_k A[k][u]*B[k][v]) batched over 8
// 32x32 tiles -> 512 blocks; register-prefetched staging hides L2 latency.
// ============================================================================
template<int EPI>
__launch_bounds__(256)
__global__ void gemm256c(float* __restrict__ D, const float* __restrict__ A,
                         const float* __restrict__ Bm, const float* __restrict__ E)
{
    __shared__ float As[32][36];     // +4 pad: conflict-free f4 stores / f2 reads
    __shared__ float Bs[32][36];
    const int i = blockIdx.z;
    const size_t off = (size_t)i * 65536;
    const float* Ai = A + off;
    const float* Bi = Bm + off;
    const int t  = threadIdx.x;
    const int tx = t & 15, ty = t >> 4;
    const int u0 = blockIdx.y * 32, v0 = blockIdx.x * 32;
    const int lk = t >> 3, lv = (t & 7) << 2;

    float acc[2][2] = {{0.f, 0.f}, {0.f, 0.f}};
    float4 an = *(const float4*)(Ai + (size_t)lk * 256 + u0 + lv);
    float4 bn = *(const float4*)(Bi + (size_t)lk * 256 + v0 + lv);

    for (int k0 = 0; k0 < 256; k0 += 32) {
        if (k0) __syncthreads();
        *(float4*)&As[lk][lv] = an;
        *(float4*)&Bs[lk][lv] = bn;
        if (k0 < 224) {
            an = *(const float4*)(Ai + (size_t)(k0 + 32 + lk) * 256 + u0 + lv);
            bn = *(const float4*)(Bi + (size_t)(k0 + 32 + lk) * 256 + v0 + lv);
        }
        __syncthreads();
#pragma unroll
        for (int kk = 0; kk < 32; ++kk) {
            float2 a2 = *(const float2*)&As[kk][ty * 2];
            float2 b2 = *(const float2*)&Bs[kk][tx * 2];
            acc[0][0] += a2.x * b2.x; acc[0][1] += a2.x * b2.y;
            acc[1][0] += a2.y * b2.x; acc[1][1] += a2.y * b2.y;
        }
    }

#pragma unroll
    for (int m = 0; m < 2; ++m) {
        const int u = u0 + ty * 2 + m;
        const size_t idx = off + (size_t)u * 256 + v0 + tx * 2;
        float2 r;
        if (EPI == 0) {
            r.x = acc[m][0]; r.y = acc[m][1];
        } else if (EPI == 1) {
            r.x = acc[m][0] + ((u == v0 + tx * 2)     ? 2.f : 0.f);
            r.y = acc[m][1] + ((u == v0 + tx * 2 + 1) ? 2.f : 0.f);
        } else {
            float2 e = *(const float2*)&E[idx];
            r.x = 2.f * e.x - acc[m][0];
            r.y = 2.f * e.y - acc[m][1];
        }
        *(float2*)&D[idx] = r;
    }
}

// transpose Bt[k][u] = B0[u][k] : 64 blocks (8 matrices x 8 row-slabs)
__launch_bounds__(256)
__global__ void prep_bt(const float* __restrict__ B0, float* __restrict__ Bt)
{
    __shared__ float tl[32][33];
    const int i = blockIdx.x;
    const int s = blockIdx.y;
    const float* S = B0 + (size_t)i * 65536;
    float* D = Bt + (size_t)i * 65536;
    const int t = threadIdx.x;
    const int tx = t & 31, ty = t >> 5;   // 32 x 8
    const int u0 = s * 32;
    for (int k0 = 0; k0 < 256; k0 += 32) {
        __syncthreads();
#pragma unroll
        for (int r = 0; r < 32; r += 8)
            tl[ty + r][tx] = S[(size_t)(u0 + ty + r) * 256 + k0 + tx];
        __syncthreads();
#pragma unroll
        for (int r = 0; r < 32; r += 8)
            D[(size_t)(k0 + ty + r) * 256 + u0 + tx] = tl[tx][ty + r];
    }
}

// alpha = ||C||_inf, then quadratic NS seed X0 = a I + b C (rho0 ~ 0.1)
__launch_bounds__(256)
__global__ void prep_alpha_seed(const float* __restrict__ C, float* __restrict__ X)
{
    __shared__ float red[256];
    const int i = blockIdx.x;
    const int t = threadIdx.x;
    float s = 0.f;
    for (int v = 0; v < 256; ++v) s += fabsf(C[(size_t)i * 65536 + (size_t)v * 256 + t]);
    red[t] = s;
    __syncthreads();
    for (int off = 128; off > 0; off >>= 1) {
        if (t < off) red[t] = fmaxf(red[t], red[t + off]);
        __syncthreads();
    }
    const float bt = red[0];                       // >= lambda_max; lambda_min >= 2
    const float r = (2.f + bt) * (2.f + bt) / (8.f * bt);
    const float e = (r - 1.f) / (r + 1.f);
    const float b = -(1.f - e) / (2.f * bt);
    const float a = -b * (2.f + bt);
    for (int idx = t; idx < 65536; idx += 256) {
        const int r_ = idx >> 8, c_ = idx & 255;
        X[(size_t)i * 65536 + idx] = b * C[(size_t)i * 65536 + idx] + ((r_ == c_) ? a : 0.f);
    }
}

// bq = 0.1*B0^T q, c1 = M bq (cc slots 256..511), c0 = 0.1 q - B c1 (0..255)
__launch_bounds__(256)
__global__ void prep_cc2(const float* __restrict__ M, const float* __restrict__ Bt,
                         const float* __restrict__ B0, const float* __restrict__ q,
                         float* __restrict__ cc)
{
    __shared__ float qs[256];
    __shared__ float vs[256];
    __shared__ float c1s[256];
    const int i = blockIdx.x;
    const int u = threadIdx.x;
    qs[u] = q[i * 256 + u];
    __syncthreads();
    float s0 = 0.f;
    for (int k = 0; k < 256; ++k) s0 += B0[(size_t)i * 65536 + (size_t)k * 256 + u] * qs[k];
    vs[u] = 0.1f * s0;
    __syncthreads();
    float s = 0.f;
    for (int k = 0; k < 256; ++k) s += M[(size_t)i * 65536 + (size_t)k * 256 + u] * vs[k];
    c1s[u] = s;
    cc[i * 512 + 256 + u] = s;
    __syncthreads();
    float s2 = 0.f;
    for (int k = 0; k < 256; ++k) s2 += Bt[(size_t)i * 65536 + (size_t)k * 256 + u] * c1s[k];
    cc[i * 512 + u] = 0.1f * qs[u] - s2;
}

// Wc[i][c][512] f16 pack: c<256 -> z0 row u=c, c>=256 -> z1 row u=c-256
__launch_bounds__(256)
__global__ void pack_wcomb(const float* __restrict__ P, const float* __restrict__ R,
                           const float* __restrict__ M, u16* __restrict__ W)
{
    const int i = blockIdx.y;
    const int e = blockIdx.x * 256 + threadIdx.x;   // 0..262143
    const int c = e >> 9, k = e & 511;
    const size_t off = (size_t)i * 65536;
    float v;
    if (c < 256) {        // z0 row u=c: [I - R | -P^T]
        if (k < 256) v = ((c == k) ? 1.f : 0.f) - R[off + (size_t)c * 256 + k];
        else         v = -P[off + (size_t)(k - 256) * 256 + c];
    } else {              // z1 row u=c-256: [P | M]
        const int u = c - 256;
        if (k < 256) v = P[off + (size_t)u * 256 + k];
        else         v = M[off + (size_t)u * 256 + (k - 256)];
    }
    W[(size_t)i * 262144 + (size_t)c * 512 + k] = f2h(v);
}

// W_in [784][256] -> Wi[256 u][800 k] f16 (transposed, zero-padded)
__global__ void pack_win(const float* __restrict__ Wsrc, u16* __restrict__ W)
{
    int k = blockIdx.x * 256 + threadIdx.x;
    int u = blockIdx.y;
    if (k >= 800) return;
    float v = (k < 784) ? Wsrc[(size_t)k * 256 + u] : 0.f;
    W[(size_t)u * 800 + k] = f2h(v);
}

extern "C" void kernel_launch(void* const* d_in, const int* in_sizes, int n_in,
                              void* d_out, int out_size, void* d_ws, size_t ws_size,
                              hipStream_t stream)
{
    const float* x     = (const float*)d_in[0];
    const float* W_in  = (const float*)d_in[1];
    const float* b_in  = (const float*)d_in[2];
    const float* B0    = (const float*)d_in[3];
    const float* q     = (const float*)d_in[4];
    const float* W_out = (const float*)d_in[5];
    const float* b_out = (const float*)d_in[6];

    u16* Wc = (u16*)d_ws;                  // 8 * 262144 u16 = 4 MB
    u16* Wi = Wc + 8 * 262144;             // 256*800 u16
    float* cc = (float*)(Wi + 204800);     // 8*512 floats
    float* F  = cc + 4096;                 // prep scratch: 7 * 524288 floats
    float* Bt = F;
    float* C  = F + 1 * 524288;
    float* X  = F + 2 * 524288;
    float* X2 = F + 3 * 524288;
    float* Y  = F + 4 * 524288;
    float* P  = F + 5 * 524288;
    float* R  = F + 6 * 524288;

    // ---- per-layer matrix prep (fp32) ----
    prep_bt<<<dim3(8, 8), 256, 0, stream>>>(B0, Bt);
    gemm256c<1><<<dim3(8, 8, 8), 256, 0, stream>>>(C, B0, B0, nullptr); // C = B^T B + 2I
    prep_alpha_seed<<<8, 256, 0, stream>>>(C, X);
    float* Xc = X; float* Xn = X2;
    for (int it = 0; it < 3; ++it) {   // Newton-Schulz: X <- 2X - X C X
        gemm256c<0><<<dim3(8, 8, 8), 256, 0, stream>>>(Y, C, Xc, nullptr);
        gemm256c<2><<<dim3(8, 8, 8), 256, 0, stream>>>(Xn, Xc, Y, Xc);
        float* tmp = Xc; Xc = Xn; Xn = tmp;
    }
    // Xc = M = (B^T B + 2I)^{-1} (symmetric)
    gemm256c<0><<<dim3(8, 8, 8), 256, 0, stream>>>(P, Xc, Bt, nullptr);  // P = M B^T
    gemm256c<0><<<dim3(8, 8, 8), 256, 0, stream>>>(R, Bt, P, nullptr);   // R = B P
    prep_cc2<<<8, 256, 0, stream>>>(Xc, Bt, B0, q, cc);

    // ---- weight packs ----
    pack_wcomb<<<dim3(1024, 8), 256, 0, stream>>>(P, R, Xc, Wc);
    pack_win<<<dim3(4, 256), 256, 0, stream>>>(W_in, Wi);

    // ---- the whole network in one kernel ----
    meganet<<<BATCH_N / 128, 1024, 0, stream>>>(
        x, Wi, b_in, Wc, cc, W_out, b_out, (float*)d_out);
}